// Round 4
// baseline (205.760 us; speedup 1.0000x reference)
//
#include <hip/hip_runtime.h>
#include <stdint.h>

#define NF 27
#define ND 128
#define OUTW 479          // 128 + 27*26/2
#define WAVES 4

typedef float f32x4 __attribute__((ext_vector_type(4)));
typedef short s16x8 __attribute__((ext_vector_type(8)));

__device__ __forceinline__ unsigned short f2bf(float x) {
    union { float f; uint32_t u; } c; c.f = x;
    uint32_t u = c.u;
    u += 0x7fffu + ((u >> 16) & 1u);   // RNE round to bf16
    return (unsigned short)(u >> 16);
}

__device__ __forceinline__ s16x8 pack8(float4 a, float4 b) {
    s16x8 r;
    r[0] = (short)f2bf(a.x); r[1] = (short)f2bf(a.y);
    r[2] = (short)f2bf(a.z); r[3] = (short)f2bf(a.w);
    r[4] = (short)f2bf(b.x); r[5] = (short)f2bf(b.y);
    r[6] = (short)f2bf(b.z); r[7] = (short)f2bf(b.w);
    return r;
}

__global__ __launch_bounds__(256) void dot_interact_kernel(
    const float* __restrict__ feat,
    const float* __restrict__ bottom,
    float* __restrict__ out, int B)
{
    const int tid  = threadIdx.x;
    const int lane = tid & 63;
    const int b    = blockIdx.x * WAVES + (tid >> 6);
    if (b >= B) return;

    // ---- MFMA fragments loaded directly from global (no LDS, no barrier) ----
    // A/B frag layout for mfma_f32_16x16x32_bf16: row/col = lane&15,
    // k-octet = (lane>>4)*8 within each 32-wide k-step.
    const int rsel = lane & 15;
    const int kg   = (lane >> 4) * 8;
    const int row1 = (rsel + 16 < NF) ? rsel + 16 : NF - 1;  // clamp: rows >=27 unused
    const float* fb = feat + (size_t)b * (NF * ND);
    const float* p0 = fb + rsel * ND + kg;
    const float* p1 = fb + row1 * ND + kg;

    f32x4 acc00 = {0.f,0.f,0.f,0.f};
    f32x4 acc10 = {0.f,0.f,0.f,0.f};
    f32x4 acc11 = {0.f,0.f,0.f,0.f};
    #pragma unroll
    for (int ks = 0; ks < 4; ++ks) {
        float4 a0 = *(const float4*)(p0 + ks * 32);
        float4 a1 = *(const float4*)(p0 + ks * 32 + 4);
        float4 b0 = *(const float4*)(p1 + ks * 32);
        float4 b1 = *(const float4*)(p1 + ks * 32 + 4);
        s16x8 fr0 = pack8(a0, a1);
        s16x8 fr1 = pack8(b0, b1);
        acc00 = __builtin_amdgcn_mfma_f32_16x16x32_bf16(fr0, fr0, acc00, 0, 0, 0);
        acc10 = __builtin_amdgcn_mfma_f32_16x16x32_bf16(fr1, fr0, acc10, 0, 0, 0);
        acc11 = __builtin_amdgcn_mfma_f32_16x16x32_bf16(fr1, fr1, acc11, 0, 0, 0);
    }

    float* ob = out + (size_t)b * OUTW;

    // ---- bottom_mlp_out copy (coalesced) ----
    const float* bb = bottom + (size_t)b * ND;
    ob[lane]      = bb[lane];
    ob[lane + 64] = bb[lane + 64];

    // ---- tril scatter: C/D layout col=lane&15, row=(lane>>4)*4+e ----
    const int jj = lane & 15;
    const int r0 = (lane >> 4) * 4;
    #pragma unroll
    for (int e = 0; e < 4; ++e) {
        int i0 = r0 + e;                       // tile (0,0): i 0..15, j 0..15
        if (jj < i0) ob[128 + (i0 * (i0 - 1)) / 2 + jj] = acc00[e];
        int i1 = i0 + 16;                      // tiles (1,0)/(1,1): i 16..26
        if (i1 < NF) {
            ob[128 + (i1 * (i1 - 1)) / 2 + jj] = acc10[e];          // j 0..15 < i
            int j1 = jj + 16;
            if (j1 < i1) ob[128 + (i1 * (i1 - 1)) / 2 + j1] = acc11[e];
        }
    }
}

extern "C" void kernel_launch(void* const* d_in, const int* in_sizes, int n_in,
                              void* d_out, int out_size, void* d_ws, size_t ws_size,
                              hipStream_t stream) {
    const float* feat   = (const float*)d_in[0];
    const float* bottom = (const float*)d_in[1];
    float* out          = (float*)d_out;
    const int B = in_sizes[0] / (NF * ND);
    const int grid = (B + WAVES - 1) / WAVES;
    dot_interact_kernel<<<grid, 256, 0, stream>>>(feat, bottom, out, B);
}